// Round 7
// baseline (309.653 us; speedup 1.0000x reference)
//
#include <hip/hip_runtime.h>
#include <math.h>

// Problem constants
#define BB 4
#define CC 64
#define HH 128
#define WW 128
#define GG 8
#define COO 64
#define HWC (HH*WW)

// Deform LDS layout: pixel stride 12 u32 (48 B, 16B aligned), row padded to 26
#define DPAD 12
#define DROW 26

typedef float f32x4 __attribute__((ext_vector_type(4)));
typedef __bf16 bf16x8 __attribute__((ext_vector_type(8)));

__device__ __forceinline__ unsigned short bf16_rn(float f) {
    unsigned int u = __float_as_uint(f);
    unsigned int r = (u + 0x7fffu + ((u >> 16) & 1u)) >> 16;
    return (unsigned short)r;
}
__device__ __forceinline__ float b2f(unsigned short u) {
    return __uint_as_float(((unsigned int)u) << 16);
}

// ---------------------------------------------------------------------------
// Fused input pack: one launch produces
//   xs   : NCHW u32 {lo=bf16(x), hi=bf16(share)}   (deform source)
//   sc16 : share in c16 layout [((b*4+cg)*HWC+pix)*16+ci]  (conv B)
//   oc16 : offset_feat in c16 layout                       (conv B)
// ---------------------------------------------------------------------------
__global__ __launch_bounds__(256) void pack_inputs_kernel(
    const float* __restrict__ x, const float* __restrict__ share,
    const float* __restrict__ offf,
    unsigned int* __restrict__ xs, unsigned short* __restrict__ sc16,
    unsigned short* __restrict__ oc16)
{
    __shared__ unsigned short lds[64][66];
    const int b = blockIdx.y;
    const int pix0 = blockIdx.x * 64;
    const int t = threadIdx.x;
    const int p = t & 63, q = t >> 6;
    const int pl = t & 63, cg = t >> 6;

    // Phase 1: share -> lds + xs write (share & x elementwise)
#pragma unroll
    for (int i = 0; i < 16; i++) {
        int c = i * 4 + q;
        size_t idx = ((size_t)b * 64 + c) * HWC + pix0 + p;
        unsigned short sb = bf16_rn(share[idx]);
        lds[c][p] = sb;
        xs[idx] = (unsigned int)bf16_rn(x[idx]) | ((unsigned int)sb << 16);
    }
    __syncthreads();
    {
        unsigned int u[8];
#pragma unroll
        for (int j = 0; j < 8; j++) {
            unsigned int lo = lds[cg * 16 + 2 * j][pl];
            unsigned int hi = lds[cg * 16 + 2 * j + 1][pl];
            u[j] = lo | (hi << 16);
        }
        unsigned int* dst = (unsigned int*)(sc16 + ((size_t)(b * 4 + cg) * HWC + pix0 + pl) * 16);
        *(uint4*)dst = make_uint4(u[0], u[1], u[2], u[3]);
        *(uint4*)(dst + 4) = make_uint4(u[4], u[5], u[6], u[7]);
    }
    __syncthreads();

    // Phase 2: offset_feat -> lds -> oc16
#pragma unroll
    for (int i = 0; i < 16; i++) {
        int c = i * 4 + q;
        lds[c][p] = bf16_rn(offf[((size_t)b * 64 + c) * HWC + pix0 + p]);
    }
    __syncthreads();
    {
        unsigned int u[8];
#pragma unroll
        for (int j = 0; j < 8; j++) {
            unsigned int lo = lds[cg * 16 + 2 * j][pl];
            unsigned int hi = lds[cg * 16 + 2 * j + 1][pl];
            u[j] = lo | (hi << 16);
        }
        unsigned int* dst = (unsigned int*)(oc16 + ((size_t)(b * 4 + cg) * HWC + pix0 + pl) * 16);
        *(uint4*)dst = make_uint4(u[0], u[1], u[2], u[3]);
        *(uint4*)(dst + 4) = make_uint4(u[4], u[5], u[6], u[7]);
    }
}

// ---------------------------------------------------------------------------
// Weight packs for 16x16x32 MFMA fragments.
// Layout: wp[(t*(COP/16)+cob)*64 + lane][8] bf16, where t = seg*18 + kk*2 + ks,
// lane holds co = cob*16+(lane&15), k_local = (lane>>4)*8 + j (j=0..7),
// cg = 2*ks + (k_local>>4), ci = k_local&15, cin = seg*64 + cg*16 + ci.
// A 32-co step-slice (t, cb0..cb0+1) is a contiguous 2 KB block.
// Sizes: om 18*256*32=147456, em1 36*64*32=73728, em2 18*128*32=73728.
// ---------------------------------------------------------------------------
__device__ __forceinline__ void pack_w_one(const float* __restrict__ w,
                                           unsigned short* __restrict__ wp,
                                           int Cout, int COP, int CinTot, int idx) {
    int j    = idx & 7;
    int lane = (idx >> 3) & 63;
    int rem  = idx >> 9;              // t*(COP/16) + cob
    int ncob = COP >> 4;
    int cob  = rem % ncob;
    int t    = rem / ncob;
    int seg  = t / 18;
    int tt   = t % 18;
    int kk   = tt >> 1;
    int ks   = tt & 1;
    int co   = cob * 16 + (lane & 15);
    int kl   = ((lane >> 4) << 3) + j;     // 0..31
    int cg   = ks * 2 + (kl >> 4);
    int ci   = kl & 15;
    int cin  = seg * 64 + cg * 16 + ci;
    float v = (co < Cout) ? w[((size_t)co * CinTot + cin) * 9 + kk] : 0.f;
    wp[idx] = bf16_rn(v);
}

__global__ void pack_w_all_kernel(const float* __restrict__ w_om, unsigned short* __restrict__ wp_om,
                                  const float* __restrict__ w_em1, unsigned short* __restrict__ wp_em1,
                                  const float* __restrict__ w_em2, unsigned short* __restrict__ wp_em2) {
    int i = blockIdx.x * 256 + threadIdx.x;
    if (i < 147456) {
        pack_w_one(w_om, wp_om, 216, 256, 64, i);
    } else if (i < 147456 + 73728) {
        pack_w_one(w_em1, wp_em1, 64, 64, 128, i - 147456);
    } else if (i < 147456 + 73728 + 73728) {
        pack_w_one(w_em2, wp_em2, 72, 128, 64, i - 147456 - 73728);
    }
}

// ---------------------------------------------------------------------------
// Implicit-GEMM 3x3 conv via mfma_f32_16x16x32_bf16, inputs in c16 layout.
// R12 structure (unchanged this round): all operands staged in LDS once,
// one barrier, pure-LDS 18-step K-loop with immediate offsets, no barriers.
// ---------------------------------------------------------------------------
template<int NSEG, int COP, int XS>
__global__ __launch_bounds__(256) void conv_mfma_kernel(
    const unsigned short* __restrict__ in0,
    const unsigned short* __restrict__ in1,
    const unsigned short* __restrict__ wp,
    const float* __restrict__ bias,
    void* __restrict__ out,
    int Cout, int out_mode, int act)
{
    constexpr int PXT = 128 / XS;      // output px per block (32)
    constexpr int NT  = PXT / 16;      // B-frags per step (2)
    constexpr int PXW = PXT + 2;       // staged px incl. halo (34)
    constexpr int NE  = 4 * 6 * PXW;   // input entries of 32 B (816)
    constexpr int NCB = COP >> 4;
    __shared__ __align__(16) unsigned short slds[NE * 16];     // 26112 B
    __shared__ __align__(16) unsigned short wlds[18 * 1024];   // 36864 B

    const int tix  = threadIdx.x;
    const int lane = tix & 63;
    const int wid  = tix >> 6;
    int tmp = blockIdx.x;
    const int xsp = tmp % XS; tmp /= XS;
    const int rb  = tmp & 31;              // HH/4 = 32
    const int b   = tmp >> 5;
    const int r0  = rb * 4;
    const int r   = r0 + wid;              // output row, wave-uniform
    const int px0 = xsp * PXT;
    const int cb0 = blockIdx.y * 2;        // co block-of-16 base (32-co slice)
    const int co0 = blockIdx.y * 32;

    f32x4 acc[2][NT];
#pragma unroll
    for (int cob = 0; cob < 2; cob++)
#pragma unroll
        for (int nt = 0; nt < NT; nt++)
#pragma unroll
            for (int rg = 0; rg < 4; rg++) acc[cob][nt][rg] = 0.f;

    // B-fragment lane mapping for 16x16x32: col(px)=lane&15, k=(lane>>4)*8+j.
    const int pxl  = lane & 15;
    const int kgrp = lane >> 4;            // 0..3
    const int cglh = lane >> 5;            // cg within pair
    const int cil0 = (kgrp & 1) * 8;       // ci half
    const unsigned short* lp = slds +
        ((size_t)(cglh * 6 + wid) * PXW + 1 + pxl) * 16 + cil0;
    const unsigned short* ap = wlds + lane * 8;

#pragma unroll
    for (int seg = 0; seg < NSEG; seg++) {
        const unsigned short* inb = (seg ? in1 : in0) + (size_t)b * 4 * HWC * 16;
        if (seg) __syncthreads();

        // ---- Stage weight slice: 18 steps x 2 cob x 1 KB = 36864 B ----
#pragma unroll
        for (int i = 0; i < 9; i++) {
            const int idx = tix + i * 256;
            const int tl  = idx >> 7;          // step 0..17
            const int c   = idx & 127;         // 16B chunk within 2 KB slice
            const uint4 v = *(const uint4*)(wp +
                ((size_t)((seg * 18 + tl) * NCB + cb0) * 512) + c * 8);
            *(uint4*)(wlds + (size_t)tl * 1024 + c * 8) = v;
        }

        // ---- Stage input tile: 4 cg x 6 rows x PXW px, zero-padded ----
#pragma unroll
        for (int i = 0; i < (NE + 255) / 256; i++) {
            const int e = tix + i * 256;
            if (i < NE / 256 || e < NE) {
                const int cg  = e / (6 * PXW);
                const int rem = e - cg * (6 * PXW);
                const int row = rem / PXW;
                const int px  = rem - row * PXW;
                const int iy = r0 - 1 + row;
                const int ix = px0 - 1 + px;
                const bool valid = ((unsigned)iy < (unsigned)HH) && ((unsigned)ix < (unsigned)WW);
                const int iyc = min(max(iy, 0), HH - 1);
                const int ixc = min(max(ix, 0), WW - 1);
                const uint4* src = (const uint4*)(inb + ((size_t)cg * HWC + (size_t)iyc * WW + ixc) * 16);
                uint4 v0, v1;
                if (valid) { v0 = src[0]; v1 = src[1]; }
                else       { v0 = make_uint4(0u, 0u, 0u, 0u); v1 = v0; }
                uint4* dst = (uint4*)(slds + (size_t)e * 16);
                dst[0] = v0; dst[1] = v1;
            }
        }
        __syncthreads();

        // ---- Pure-LDS K loop: 18 steps, no barriers, no global ----
#pragma unroll
        for (int t = 0; t < 18; t++) {
            const int kk = t >> 1, ks = t & 1;
            const int kh = kk / 3, kw = kk % 3;
            bf16x8 af[2];
#pragma unroll
            for (int cob = 0; cob < 2; cob++)
                af[cob] = *(const bf16x8*)(ap + t * 1024 + cob * 512);
            bf16x8 bf[NT];
#pragma unroll
            for (int nt = 0; nt < NT; nt++)
                bf[nt] = *(const bf16x8*)(lp +
                    ((ks * 12 + kh) * PXW + nt * 16 + kw - 1) * 16);
#pragma unroll
            for (int cob = 0; cob < 2; cob++)
#pragma unroll
                for (int nt = 0; nt < NT; nt++)
                    acc[cob][nt] = __builtin_amdgcn_mfma_f32_16x16x32_bf16(
                        af[cob], bf[nt], acc[cob][nt], 0, 0, 0);
        }
    }

    // Epilogue: 16x16 D layout col(px)=lane&15, row(co)=(lane>>4)*4+rg
#pragma unroll
    for (int cob = 0; cob < 2; cob++) {
#pragma unroll
        for (int nt = 0; nt < NT; nt++) {
#pragma unroll
            for (int rg = 0; rg < 4; rg++) {
                const int co = co0 + cob * 16 + kgrp * 4 + rg;
                if (co < Cout) {
                    float v = acc[cob][nt][rg] + bias[co];
                    if (act == 1)      v = (v >= 0.f) ? v : 0.1f * v;
                    else if (act == 2) v = 1.f / (1.f + __expf(-v));
                    else if (act == 3 && co >= 144) v = 1.f / (1.f + __expf(-v));
                    const int pix = r * WW + px0 + nt * 16 + pxl;
                    if (out_mode == 2)
                        ((unsigned short*)out)[((size_t)b * Cout + co) * HWC + pix] = bf16_rn(v);
                    else // c16
                        ((unsigned short*)out)[((size_t)(b * 4 + (co >> 4)) * HWC + pix) * 16 + (co & 15)] = bf16_rn(v);
                }
            }
        }
    }
}

// ---------------------------------------------------------------------------
// Fused dual modulated deformable conv.
// R13: kill the per-tap dependent global loads. Old loop issued 4 scalar
// strided loads (dy,dx,m1,m2) per tap + 576 global weight loads per thread;
// VGPR=52 shows the allocator sank them all -> ~36 serial latency events at
// 35% VALUBusy. Fix: cooperatively stage the block's 36 om/em planes
// (36 x 256 px, 18.4 KB), and wdc for this g (576 f32, 2.3 KB), into LDS
// with independent coalesced loads and ONE barrier. Tap loop becomes pure
// VALU + conflict-free LDS (uniform-plane reads = 2-way broadcast, free).
// Math is bit-identical; only the data path changed.
// ---------------------------------------------------------------------------
__global__ __launch_bounds__(256) void deform_fused_kernel(
    const unsigned int* __restrict__ xs,
    const unsigned short* __restrict__ om, const unsigned short* __restrict__ em,
    const float* __restrict__ wdc, const float* __restrict__ bdc,
    float* __restrict__ outx, float* __restrict__ outs)
{
    __shared__ __align__(16) unsigned int lds[24 * DROW * DPAD];   // 29952 B
    __shared__ __align__(4) unsigned short plds[36 * 256];         // 18432 B
    __shared__ __align__(16) float wlds[576];                      // 2304 B

    const int bg = blockIdx.x >> 6;           // b*8+g
    const int b = bg >> 3, g = bg & 7;
    const int tile = blockIdx.x & 63;
    const int r0 = (tile >> 3) << 4;
    const int c0 = (tile & 7) << 4;
    const int tix = threadIdx.x;
    const int tx = tix & 15, ty = tix >> 4;
    const int h = r0 + ty, w = c0 + tx;
    const int wr0 = r0 - 4, wc0 = c0 - 4;

    const unsigned int* xsb = xs + ((size_t)b * 64 + g * 8) * HWC;

    // ---- Stage xs window: 24x24x8ch u32 ----
#pragma unroll
    for (int i = 0; i < 18; i++) {
        unsigned int slot = (unsigned int)tix + i * 256u;   // 0..4607
        unsigned int sx = slot % 24u;
        unsigned int t2 = slot / 24u;
        unsigned int sy = t2 % 24u;
        unsigned int c  = t2 / 24u;
        int iy = min(max(wr0 + (int)sy, 0), HH - 1);
        int ix = min(max(wc0 + (int)sx, 0), WW - 1);
        lds[(sy * DROW + sx) * DPAD + c] = xsb[(size_t)c * HWC + iy * WW + ix];
    }

    // ---- Stage om/em planes: 36 planes x 256 px (2 px per u32 load) ----
    // Plane map: 0..17 = om ch g*18+c (dy/dx pairs); 18..26 = om ch
    // 144+g*9+(c-18) (mask m1); 27..35 = em ch g*9+(c-27) (mask m2).
    {
        const unsigned short* omc = om + (size_t)b * 216 * HWC;
        const unsigned short* emc = em + (size_t)b * 72 * HWC;
#pragma unroll
        for (int k = 0; k < 18; k++) {
            const int i   = tix + k * 256;
            const int c   = i >> 7;           // plane 0..35
            const int rem = i & 127;          // u32 index within plane
            const int py  = rem >> 3;
            const int px  = (rem & 7) * 2;
            const unsigned short* src;
            if (c < 18)      src = omc + (size_t)(g * 18 + c) * HWC;
            else if (c < 27) src = omc + (size_t)(144 + g * 9 + (c - 18)) * HWC;
            else             src = emc + (size_t)(g * 9 + (c - 27)) * HWC;
            const unsigned int v = *(const unsigned int*)(src +
                (size_t)(r0 + py) * WW + (c0 + px));
            *(unsigned int*)(plds + c * 256 + rem * 2) = v;
        }
    }
    // ---- Stage wdc for this g: 576 f32 = 144 float4 ----
    if (tix < 144)
        ((float4*)wlds)[tix] = ((const float4*)(wdc + (size_t)g * 576))[tix];

    __syncthreads();

    const int pix = h * WW + w;

    float accx[8], accs[8];
#pragma unroll
    for (int o = 0; o < 8; o++) { accx[o] = 0.f; accs[o] = 0.f; }

#pragma unroll
    for (int kk = 0; kk < 9; kk++) {
        const float dy = b2f(plds[(2 * kk) * 256 + tix]);
        const float dx = b2f(plds[(2 * kk + 1) * 256 + tix]);
        const float m1 = b2f(plds[(18 + kk) * 256 + tix]);
        const float m2 = b2f(plds[(27 + kk) * 256 + tix]);

        const float py = (float)(h - 1 + kk / 3) + dy;
        const float px = (float)(w - 1 + kk % 3) + dx;
        const float y0f = floorf(py), x0f = floorf(px);
        const float ly = py - y0f, lx = px - x0f;
        const int y0 = (int)y0f, x0 = (int)x0f;
        const int y1 = y0 + 1, x1 = x0 + 1;
        const bool vy0 = (y0 >= 0) && (y0 < HH), vy1 = (y1 >= 0) && (y1 < HH);
        const bool vx0 = (x0 >= 0) && (x0 < WW), vx1 = (x1 >= 0) && (x1 < WW);
        float w00 = (1.f - ly) * (1.f - lx); if (!(vy0 && vx0)) w00 = 0.f;
        float w01 = (1.f - ly) * lx;         if (!(vy0 && vx1)) w01 = 0.f;
        float w10 = ly * (1.f - lx);         if (!(vy1 && vx0)) w10 = 0.f;
        float w11 = ly * lx;                 if (!(vy1 && vx1)) w11 = 0.f;
        const int cy0 = min(max(y0, 0), HH - 1), cy1 = min(max(y1, 0), HH - 1);
        const int cx0 = min(max(x0, 0), WW - 1), cx1 = min(max(x1, 0), WW - 1);

        const int sy0 = cy0 - wr0, sy1 = cy1 - wr0;
        const int sx0 = cx0 - wc0, sx1 = cx1 - wc0;
        const bool inw = (sy0 >= 0) && (sy1 < 24) && (sx0 >= 0) && (sx1 < 24);

        const float* wk = wlds + kk;   // wk[(o*8+c)*9]

        if (__builtin_expect(inw, 1)) {
            const int p00 = (sy0 * DROW + sx0) * DPAD, p01 = (sy0 * DROW + sx1) * DPAD;
            const int p10 = (sy1 * DROW + sx0) * DPAD, p11 = (sy1 * DROW + sx1) * DPAD;
#pragma unroll
            for (int ch = 0; ch < 2; ch++) {
                uint4 qa = *(const uint4*)(lds + p00 + ch * 4);
                uint4 qb = *(const uint4*)(lds + p01 + ch * 4);
                uint4 qc = *(const uint4*)(lds + p10 + ch * 4);
                uint4 qd = *(const uint4*)(lds + p11 + ch * 4);
                const unsigned int ua[4] = {qa.x, qa.y, qa.z, qa.w};
                const unsigned int ub[4] = {qb.x, qb.y, qb.z, qb.w};
                const unsigned int uc[4] = {qc.x, qc.y, qc.z, qc.w};
                const unsigned int ud[4] = {qd.x, qd.y, qd.z, qd.w};
#pragma unroll
                for (int j = 0; j < 4; j++) {
                    const int c = ch * 4 + j;
                    float x00 = __uint_as_float(ua[j] << 16), s00 = __uint_as_float(ua[j] & 0xffff0000u);
                    float x01 = __uint_as_float(ub[j] << 16), s01 = __uint_as_float(ub[j] & 0xffff0000u);
                    float x10 = __uint_as_float(uc[j] << 16), s10 = __uint_as_float(uc[j] & 0xffff0000u);
                    float x11 = __uint_as_float(ud[j] << 16), s11 = __uint_as_float(ud[j] & 0xffff0000u);
                    float vx = w00 * x00; vx = fmaf(w01, x01, vx); vx = fmaf(w10, x10, vx); vx = fmaf(w11, x11, vx);
                    float vs = w00 * s00; vs = fmaf(w01, s01, vs); vs = fmaf(w10, s10, vs); vs = fmaf(w11, s11, vs);
                    vx *= m1;
                    vs *= m2;
#pragma unroll
                    for (int o = 0; o < 8; o++) {
                        const float wv = wk[(size_t)(o * 8 + c) * 9];
                        accx[o] = fmaf(vx, wv, accx[o]);
                        accs[o] = fmaf(vs, wv, accs[o]);
                    }
                }
            }
        } else {
            const int i00 = cy0 * WW + cx0, i01 = cy0 * WW + cx1;
            const int i10 = cy1 * WW + cx0, i11 = cy1 * WW + cx1;
#pragma unroll
            for (int c = 0; c < 8; c++) {
                const unsigned int* xc = xsb + (size_t)c * HWC;
                unsigned int a = xc[i00], bq = xc[i01], cq = xc[i10], dq = xc[i11];
                float x00 = __uint_as_float(a << 16),  s00 = __uint_as_float(a & 0xffff0000u);
                float x01 = __uint_as_float(bq << 16), s01 = __uint_as_float(bq & 0xffff0000u);
                float x10 = __uint_as_float(cq << 16), s10 = __uint_as_float(cq & 0xffff0000u);
                float x11 = __uint_as_float(dq << 16), s11 = __uint_as_float(dq & 0xffff0000u);
                float vx = w00 * x00; vx = fmaf(w01, x01, vx); vx = fmaf(w10, x10, vx); vx = fmaf(w11, x11, vx);
                float vs = w00 * s00; vs = fmaf(w01, s01, vs); vs = fmaf(w10, s10, vs); vs = fmaf(w11, s11, vs);
                vx *= m1;
                vs *= m2;
#pragma unroll
                for (int o = 0; o < 8; o++) {
                    const float wv = wk[(size_t)(o * 8 + c) * 9];
                    accx[o] = fmaf(vx, wv, accx[o]);
                    accs[o] = fmaf(vs, wv, accs[o]);
                }
            }
        }
    }

#pragma unroll
    for (int o = 0; o < 8; o++) {
        const float bv = bdc[g * 8 + o];
        outx[((size_t)(b * COO + g * 8 + o)) * HWC + pix] = accx[o] + bv;
        outs[((size_t)(b * COO + g * 8 + o)) * HWC + pix] = accs[o] + bv;
    }
}

// ---------------------------------------------------------------------------
extern "C" void kernel_launch(void* const* d_in, const int* in_sizes, int n_in,
                              void* d_out, int out_size, void* d_ws, size_t ws_size,
                              hipStream_t stream) {
    const float* x      = (const float*)d_in[0];
    const float* share  = (const float*)d_in[1];
    const float* offf   = (const float*)d_in[2];
    const float* w_om   = (const float*)d_in[3];
    const float* b_om   = (const float*)d_in[4];
    const float* w_em1  = (const float*)d_in[5];
    const float* b_em1  = (const float*)d_in[6];
    const float* w_em2  = (const float*)d_in[7];
    const float* b_em2  = (const float*)d_in[8];
    const float* w_dc   = (const float*)d_in[9];
    const float* b_dc   = (const float*)d_in[10];

    // Workspace layout
    unsigned int* xs = (unsigned int*)d_ws;           // 4194304 u32
    unsigned short* us = (unsigned short*)(xs + 4194304);
    unsigned short* sc16   = us;                      // 4194304 ush (share c16)
    unsigned short* oc16   = sc16 + 4194304;          // 4194304 (offf c16)
    unsigned short* emm    = oc16 + 4194304;          // 4194304 (em_mid c16)
    unsigned short* om_b   = emm + 4194304;           // 14155776 (om NCHW bf16)
    unsigned short* em_b   = om_b + 14155776;         // 4718592 (em NCHW bf16)
    unsigned short* wp_om  = em_b + 4718592;          // 147456 (COP=256)
    unsigned short* wp_em1 = wp_om + 147456;          // 73728  (COP=64)
    unsigned short* wp_em2 = wp_em1 + 73728;          // 73728  (COP=128)

    float* outx = (float*)d_out;
    float* outs = outx + 4194304;

    dim3 blk(256);

    // Fused input + weight packing (2 launches)
    pack_inputs_kernel<<<dim3(HWC / 64, BB), blk, 0, stream>>>(x, share, offf, xs, sc16, oc16);
    pack_w_all_kernel<<<(147456 + 73728 + 73728) / 256, blk, 0, stream>>>(
        w_om, wp_om, w_em1, wp_em1, w_em2, wp_em2);

    // om = conv(offset_feat) 64->216, sigmoid on mask channels, NCHW bf16
    conv_mfma_kernel<1, 256, 4><<<dim3(BB * 32 * 4, 7), blk, 0, stream>>>(
        oc16, nullptr, wp_om, b_om, om_b, 216, 2, 3);
    // em_mid = leaky(conv(concat(share, offf))) 128->64, c16 bf16
    conv_mfma_kernel<2, 64, 4><<<dim3(BB * 32 * 4, 2), blk, 0, stream>>>(
        sc16, oc16, wp_em1, b_em1, emm, 64, 3, 1);
    // em = sigmoid(conv(em_mid)) 64->72, NCHW bf16; grid.y=3 covers co<96
    conv_mfma_kernel<1, 128, 4><<<dim3(BB * 32 * 4, 3), blk, 0, stream>>>(
        emm, nullptr, wp_em2, b_em2, em_b, 72, 2, 2);

    // fused dual deformable conv (LDS-staged gathers + staged om/em/wdc)
    deform_fused_kernel<<<dim3(BB * GG * 64), blk, 0, stream>>>(
        xs, om_b, em_b, w_dc, b_dc, outx, outs);
}

// Round 8
// 299.698 us; speedup vs baseline: 1.0332x; 1.0332x over previous
//
#include <hip/hip_runtime.h>
#include <math.h>

// Problem constants
#define BB 4
#define CC 64
#define HH 128
#define WW 128
#define GG 8
#define COO 64
#define HWC (HH*WW)

// Deform LDS layout: pixel stride 12 u32 (48 B, 16B aligned), row padded to 26
#define DPAD 12
#define DROW 26

// dd (offset/mask) SoA: 4 planes x 8 slots + 1 plane x 4 slots, bf16.
// slot 0..17 = dy/dx (kk*2+d), 18..26 = m1[kk], 27..35 = m2[kk].
#define PS8 4194304   // shorts per 8-slot plane = BB*GG*HWC*8

typedef float f32x4 __attribute__((ext_vector_type(4)));
typedef __bf16 bf16x8 __attribute__((ext_vector_type(8)));

__device__ __forceinline__ unsigned short bf16_rn(float f) {
    unsigned int u = __float_as_uint(f);
    unsigned int r = (u + 0x7fffu + ((u >> 16) & 1u)) >> 16;
    return (unsigned short)r;
}
__device__ __forceinline__ float b2f(unsigned short u) {
    return __uint_as_float(((unsigned int)u) << 16);
}
// bf16 half (0=lo,1=hi) of a u32 word -> f32
__device__ __forceinline__ float ddx(unsigned int wrd, int half) {
    return half ? __uint_as_float(wrd & 0xffff0000u) : __uint_as_float(wrd << 16);
}

// ---------------------------------------------------------------------------
// Fused input pack (unchanged).
// ---------------------------------------------------------------------------
__global__ __launch_bounds__(256) void pack_inputs_kernel(
    const float* __restrict__ x, const float* __restrict__ share,
    const float* __restrict__ offf,
    unsigned int* __restrict__ xs, unsigned short* __restrict__ sc16,
    unsigned short* __restrict__ oc16)
{
    __shared__ unsigned short lds[64][66];
    const int b = blockIdx.y;
    const int pix0 = blockIdx.x * 64;
    const int t = threadIdx.x;
    const int p = t & 63, q = t >> 6;
    const int pl = t & 63, cg = t >> 6;

#pragma unroll
    for (int i = 0; i < 16; i++) {
        int c = i * 4 + q;
        size_t idx = ((size_t)b * 64 + c) * HWC + pix0 + p;
        unsigned short sb = bf16_rn(share[idx]);
        lds[c][p] = sb;
        xs[idx] = (unsigned int)bf16_rn(x[idx]) | ((unsigned int)sb << 16);
    }
    __syncthreads();
    {
        unsigned int u[8];
#pragma unroll
        for (int j = 0; j < 8; j++) {
            unsigned int lo = lds[cg * 16 + 2 * j][pl];
            unsigned int hi = lds[cg * 16 + 2 * j + 1][pl];
            u[j] = lo | (hi << 16);
        }
        unsigned int* dst = (unsigned int*)(sc16 + ((size_t)(b * 4 + cg) * HWC + pix0 + pl) * 16);
        *(uint4*)dst = make_uint4(u[0], u[1], u[2], u[3]);
        *(uint4*)(dst + 4) = make_uint4(u[4], u[5], u[6], u[7]);
    }
    __syncthreads();

#pragma unroll
    for (int i = 0; i < 16; i++) {
        int c = i * 4 + q;
        lds[c][p] = bf16_rn(offf[((size_t)b * 64 + c) * HWC + pix0 + p]);
    }
    __syncthreads();
    {
        unsigned int u[8];
#pragma unroll
        for (int j = 0; j < 8; j++) {
            unsigned int lo = lds[cg * 16 + 2 * j][pl];
            unsigned int hi = lds[cg * 16 + 2 * j + 1][pl];
            u[j] = lo | (hi << 16);
        }
        unsigned int* dst = (unsigned int*)(oc16 + ((size_t)(b * 4 + cg) * HWC + pix0 + pl) * 16);
        *(uint4*)dst = make_uint4(u[0], u[1], u[2], u[3]);
        *(uint4*)(dst + 4) = make_uint4(u[4], u[5], u[6], u[7]);
    }
}

// ---------------------------------------------------------------------------
// Weight packs for 16x16x32 MFMA fragments (unchanged).
// ---------------------------------------------------------------------------
__device__ __forceinline__ void pack_w_one(const float* __restrict__ w,
                                           unsigned short* __restrict__ wp,
                                           int Cout, int COP, int CinTot, int idx) {
    int j    = idx & 7;
    int lane = (idx >> 3) & 63;
    int rem  = idx >> 9;              // t*(COP/16) + cob
    int ncob = COP >> 4;
    int cob  = rem % ncob;
    int t    = rem / ncob;
    int seg  = t / 18;
    int tt   = t % 18;
    int kk   = tt >> 1;
    int ks   = tt & 1;
    int co   = cob * 16 + (lane & 15);
    int kl   = ((lane >> 4) << 3) + j;     // 0..31
    int cg   = ks * 2 + (kl >> 4);
    int ci   = kl & 15;
    int cin  = seg * 64 + cg * 16 + ci;
    float v = (co < Cout) ? w[((size_t)co * CinTot + cin) * 9 + kk] : 0.f;
    wp[idx] = bf16_rn(v);
}

__global__ void pack_w_all_kernel(const float* __restrict__ w_om, unsigned short* __restrict__ wp_om,
                                  const float* __restrict__ w_em1, unsigned short* __restrict__ wp_em1,
                                  const float* __restrict__ w_em2, unsigned short* __restrict__ wp_em2) {
    int i = blockIdx.x * 256 + threadIdx.x;
    if (i < 147456) {
        pack_w_one(w_om, wp_om, 216, 256, 64, i);
    } else if (i < 147456 + 73728) {
        pack_w_one(w_em1, wp_em1, 64, 64, 128, i - 147456);
    } else if (i < 147456 + 73728 + 73728) {
        pack_w_one(w_em2, wp_em2, 72, 128, 64, i - 147456 - 73728);
    }
}

// ---------------------------------------------------------------------------
// Implicit-GEMM 3x3 conv via mfma_f32_16x16x32_bf16 (R12 structure).
// out_mode: 0 = c16; 3 = dd offsets/m1 (om, co<144 -> slot co%18 of g=co/18,
// co>=144 -> slot 18+(co-144)%9 of g=(co-144)/9); 4 = dd m2 (em2, slot
// 27+co%9 of g=co/9).
// ---------------------------------------------------------------------------
template<int NSEG, int COP, int XS>
__global__ __launch_bounds__(256) void conv_mfma_kernel(
    const unsigned short* __restrict__ in0,
    const unsigned short* __restrict__ in1,
    const unsigned short* __restrict__ wp,
    const float* __restrict__ bias,
    void* __restrict__ out,
    int Cout, int out_mode, int act)
{
    constexpr int PXT = 128 / XS;      // output px per block (32)
    constexpr int NT  = PXT / 16;      // B-frags per step (2)
    constexpr int PXW = PXT + 2;       // staged px incl. halo (34)
    constexpr int NE  = 4 * 6 * PXW;   // input entries of 32 B (816)
    constexpr int NCB = COP >> 4;
    __shared__ __align__(16) unsigned short slds[NE * 16];     // 26112 B
    __shared__ __align__(16) unsigned short wlds[18 * 1024];   // 36864 B

    const int tix  = threadIdx.x;
    const int lane = tix & 63;
    const int wid  = tix >> 6;
    int tmp = blockIdx.x;
    const int xsp = tmp % XS; tmp /= XS;
    const int rb  = tmp & 31;              // HH/4 = 32
    const int b   = tmp >> 5;
    const int r0  = rb * 4;
    const int r   = r0 + wid;              // output row, wave-uniform
    const int px0 = xsp * PXT;
    const int cb0 = blockIdx.y * 2;        // co block-of-16 base (32-co slice)
    const int co0 = blockIdx.y * 32;

    f32x4 acc[2][NT];
#pragma unroll
    for (int cob = 0; cob < 2; cob++)
#pragma unroll
        for (int nt = 0; nt < NT; nt++)
#pragma unroll
            for (int rg = 0; rg < 4; rg++) acc[cob][nt][rg] = 0.f;

    const int pxl  = lane & 15;
    const int kgrp = lane >> 4;            // 0..3
    const int cglh = lane >> 5;            // cg within pair
    const int cil0 = (kgrp & 1) * 8;       // ci half
    const unsigned short* lp = slds +
        ((size_t)(cglh * 6 + wid) * PXW + 1 + pxl) * 16 + cil0;
    const unsigned short* ap = wlds + lane * 8;

#pragma unroll
    for (int seg = 0; seg < NSEG; seg++) {
        const unsigned short* inb = (seg ? in1 : in0) + (size_t)b * 4 * HWC * 16;
        if (seg) __syncthreads();

        // ---- Stage weight slice: 18 steps x 2 cob x 1 KB = 36864 B ----
#pragma unroll
        for (int i = 0; i < 9; i++) {
            const int idx = tix + i * 256;
            const int tl  = idx >> 7;          // step 0..17
            const int c   = idx & 127;         // 16B chunk within 2 KB slice
            const uint4 v = *(const uint4*)(wp +
                ((size_t)((seg * 18 + tl) * NCB + cb0) * 512) + c * 8);
            *(uint4*)(wlds + (size_t)tl * 1024 + c * 8) = v;
        }

        // ---- Stage input tile: 4 cg x 6 rows x PXW px, zero-padded ----
#pragma unroll
        for (int i = 0; i < (NE + 255) / 256; i++) {
            const int e = tix + i * 256;
            if (i < NE / 256 || e < NE) {
                const int cg  = e / (6 * PXW);
                const int rem = e - cg * (6 * PXW);
                const int row = rem / PXW;
                const int px  = rem - row * PXW;
                const int iy = r0 - 1 + row;
                const int ix = px0 - 1 + px;
                const bool valid = ((unsigned)iy < (unsigned)HH) && ((unsigned)ix < (unsigned)WW);
                const int iyc = min(max(iy, 0), HH - 1);
                const int ixc = min(max(ix, 0), WW - 1);
                const uint4* src = (const uint4*)(inb + ((size_t)cg * HWC + (size_t)iyc * WW + ixc) * 16);
                uint4 v0, v1;
                if (valid) { v0 = src[0]; v1 = src[1]; }
                else       { v0 = make_uint4(0u, 0u, 0u, 0u); v1 = v0; }
                uint4* dst = (uint4*)(slds + (size_t)e * 16);
                dst[0] = v0; dst[1] = v1;
            }
        }
        __syncthreads();

        // ---- Pure-LDS K loop: 18 steps, no barriers, no global ----
#pragma unroll
        for (int t = 0; t < 18; t++) {
            const int kk = t >> 1, ks = t & 1;
            const int kh = kk / 3, kw = kk % 3;
            bf16x8 af[2];
#pragma unroll
            for (int cob = 0; cob < 2; cob++)
                af[cob] = *(const bf16x8*)(ap + t * 1024 + cob * 512);
            bf16x8 bf[NT];
#pragma unroll
            for (int nt = 0; nt < NT; nt++)
                bf[nt] = *(const bf16x8*)(lp +
                    ((ks * 12 + kh) * PXW + nt * 16 + kw - 1) * 16);
#pragma unroll
            for (int cob = 0; cob < 2; cob++)
#pragma unroll
                for (int nt = 0; nt < NT; nt++)
                    acc[cob][nt] = __builtin_amdgcn_mfma_f32_16x16x32_bf16(
                        af[cob], bf[nt], acc[cob][nt], 0, 0, 0);
        }
    }

    // Epilogue: 16x16 D layout col(px)=lane&15, row(co)=(lane>>4)*4+rg
#pragma unroll
    for (int cob = 0; cob < 2; cob++) {
#pragma unroll
        for (int nt = 0; nt < NT; nt++) {
#pragma unroll
            for (int rg = 0; rg < 4; rg++) {
                const int co = co0 + cob * 16 + kgrp * 4 + rg;
                if (co < Cout) {
                    float v = acc[cob][nt][rg] + bias[co];
                    if (act == 1)      v = (v >= 0.f) ? v : 0.1f * v;
                    else if (act == 2) v = 1.f / (1.f + __expf(-v));
                    else if (act == 3 && co >= 144) v = 1.f / (1.f + __expf(-v));
                    const int pix = r * WW + px0 + nt * 16 + pxl;
                    if (out_mode == 0) {
                        ((unsigned short*)out)[((size_t)(b * 4 + (co >> 4)) * HWC + pix) * 16 + (co & 15)] = bf16_rn(v);
                    } else {
                        int gg, slot;
                        if (out_mode == 3) {
                            if (co < 144) { gg = co / 18; slot = co - gg * 18; }
                            else { int cm = co - 144; gg = cm / 9; slot = 18 + cm - gg * 9; }
                        } else { // 4: em2 mask
                            gg = co / 9; slot = 27 + co - gg * 9;
                        }
                        unsigned short* ddp = (unsigned short*)out;
                        const size_t base = (size_t)((b << 3) + gg) * HWC + pix;
                        if (slot < 32)
                            ddp[(size_t)(slot >> 3) * PS8 + base * 8 + (slot & 7)] = bf16_rn(v);
                        else
                            ddp[4 * (size_t)PS8 + base * 4 + (slot - 32)] = bf16_rn(v);
                    }
                }
            }
        }
    }
}

// ---------------------------------------------------------------------------
// Fused dual modulated deformable conv.
// R14: R12 structure (29952 B LDS, occupancy back to ~40%) + pixel-major
// offset/mask buffer dd. The 36 per-pixel offset/mask values arrive in
// 5 coalesced vector loads issued BEFORE the tap loop (one exposed latency
// instead of 9 dependent per-tap chains); unpack is constant-folded shifts.
// ---------------------------------------------------------------------------
__global__ __launch_bounds__(256) void deform_fused_kernel(
    const unsigned int* __restrict__ xs,
    const unsigned short* __restrict__ dd,
    const float* __restrict__ wdc, const float* __restrict__ bdc,
    float* __restrict__ outx, float* __restrict__ outs)
{
    __shared__ __align__(16) unsigned int lds[24 * DROW * DPAD];   // 29952 B

    const int bg = blockIdx.x >> 6;           // b*8+g
    const int b = bg >> 3, g = bg & 7;
    const int tile = blockIdx.x & 63;
    const int r0 = (tile >> 3) << 4;
    const int c0 = (tile & 7) << 4;
    const int tx = threadIdx.x & 15, ty = threadIdx.x >> 4;
    const int h = r0 + ty, w = c0 + tx;
    const int wr0 = r0 - 4, wc0 = c0 - 4;
    const int pix = h * WW + w;

    const unsigned int* xsb = xs + ((size_t)b * 64 + g * 8) * HWC;

    // ---- Issue the 5 offset/mask vector loads up front ----
    const unsigned short* db = dd + ((size_t)bg * HWC + pix) * 8;
    uint4 q[4];
    q[0] = *(const uint4*)(db);
    q[1] = *(const uint4*)(db + PS8);
    q[2] = *(const uint4*)(db + 2 * (size_t)PS8);
    q[3] = *(const uint4*)(db + 3 * (size_t)PS8);
    const uint2 q4 = *(const uint2*)(dd + 4 * (size_t)PS8 + ((size_t)bg * HWC + pix) * 4);

    // ---- Stage xs window: 24x24x8ch u32 ----
#pragma unroll
    for (int i = 0; i < 18; i++) {
        unsigned int slot = (unsigned int)threadIdx.x + i * 256u;   // 0..4607
        unsigned int sx = slot % 24u;
        unsigned int t2 = slot / 24u;
        unsigned int sy = t2 % 24u;
        unsigned int c  = t2 / 24u;
        int iy = min(max(wr0 + (int)sy, 0), HH - 1);
        int ix = min(max(wc0 + (int)sx, 0), WW - 1);
        lds[(sy * DROW + sx) * DPAD + c] = xsb[(size_t)c * HWC + iy * WW + ix];
    }

    __syncthreads();

    float accx[8], accs[8];
#pragma unroll
    for (int o = 0; o < 8; o++) { accx[o] = 0.f; accs[o] = 0.f; }

#pragma unroll
    for (int kk = 0; kk < 9; kk++) {
        // constant-folded slot extraction
        const int s_dy = 2 * kk, s_dx = 2 * kk + 1, s_m1 = 18 + kk, s_m2 = 27 + kk;
        const float dy = ddx(((const unsigned int*)&q[s_dy >> 3])[(s_dy & 7) >> 1], s_dy & 1);
        const float dx = ddx(((const unsigned int*)&q[s_dx >> 3])[(s_dx & 7) >> 1], s_dx & 1);
        const float m1 = ddx(((const unsigned int*)&q[s_m1 >> 3])[(s_m1 & 7) >> 1], s_m1 & 1);
        float m2;
        if (s_m2 < 32) m2 = ddx(((const unsigned int*)&q[s_m2 >> 3])[(s_m2 & 7) >> 1], s_m2 & 1);
        else           m2 = ddx(((s_m2 - 32) >> 1) ? q4.y : q4.x, s_m2 & 1);

        const float py = (float)(h - 1 + kk / 3) + dy;
        const float px = (float)(w - 1 + kk % 3) + dx;
        const float y0f = floorf(py), x0f = floorf(px);
        const float ly = py - y0f, lx = px - x0f;
        const int y0 = (int)y0f, x0 = (int)x0f;
        const int y1 = y0 + 1, x1 = x0 + 1;
        const bool vy0 = (y0 >= 0) && (y0 < HH), vy1 = (y1 >= 0) && (y1 < HH);
        const bool vx0 = (x0 >= 0) && (x0 < WW), vx1 = (x1 >= 0) && (x1 < WW);
        float w00 = (1.f - ly) * (1.f - lx); if (!(vy0 && vx0)) w00 = 0.f;
        float w01 = (1.f - ly) * lx;         if (!(vy0 && vx1)) w01 = 0.f;
        float w10 = ly * (1.f - lx);         if (!(vy1 && vx0)) w10 = 0.f;
        float w11 = ly * lx;                 if (!(vy1 && vx1)) w11 = 0.f;
        const int cy0 = min(max(y0, 0), HH - 1), cy1 = min(max(y1, 0), HH - 1);
        const int cx0 = min(max(x0, 0), WW - 1), cx1 = min(max(x1, 0), WW - 1);

        const int sy0 = cy0 - wr0, sy1 = cy1 - wr0;
        const int sx0 = cx0 - wc0, sx1 = cx1 - wc0;
        const bool inw = (sy0 >= 0) && (sy1 < 24) && (sx0 >= 0) && (sx1 < 24);

        const float* wk = wdc + (size_t)g * 8 * 8 * 9 + kk;   // wk[(o*8+c)*9]

        if (__builtin_expect(inw, 1)) {
            const int p00 = (sy0 * DROW + sx0) * DPAD, p01 = (sy0 * DROW + sx1) * DPAD;
            const int p10 = (sy1 * DROW + sx0) * DPAD, p11 = (sy1 * DROW + sx1) * DPAD;
#pragma unroll
            for (int ch = 0; ch < 2; ch++) {
                uint4 qa = *(const uint4*)(lds + p00 + ch * 4);
                uint4 qb = *(const uint4*)(lds + p01 + ch * 4);
                uint4 qc = *(const uint4*)(lds + p10 + ch * 4);
                uint4 qd = *(const uint4*)(lds + p11 + ch * 4);
                const unsigned int ua[4] = {qa.x, qa.y, qa.z, qa.w};
                const unsigned int ub[4] = {qb.x, qb.y, qb.z, qb.w};
                const unsigned int uc[4] = {qc.x, qc.y, qc.z, qc.w};
                const unsigned int ud[4] = {qd.x, qd.y, qd.z, qd.w};
#pragma unroll
                for (int j = 0; j < 4; j++) {
                    const int c = ch * 4 + j;
                    float x00 = __uint_as_float(ua[j] << 16), s00 = __uint_as_float(ua[j] & 0xffff0000u);
                    float x01 = __uint_as_float(ub[j] << 16), s01 = __uint_as_float(ub[j] & 0xffff0000u);
                    float x10 = __uint_as_float(uc[j] << 16), s10 = __uint_as_float(uc[j] & 0xffff0000u);
                    float x11 = __uint_as_float(ud[j] << 16), s11 = __uint_as_float(ud[j] & 0xffff0000u);
                    float vx = w00 * x00; vx = fmaf(w01, x01, vx); vx = fmaf(w10, x10, vx); vx = fmaf(w11, x11, vx);
                    float vs = w00 * s00; vs = fmaf(w01, s01, vs); vs = fmaf(w10, s10, vs); vs = fmaf(w11, s11, vs);
                    vx *= m1;
                    vs *= m2;
#pragma unroll
                    for (int o = 0; o < 8; o++) {
                        const float wv = wk[(size_t)(o * 8 + c) * 9];
                        accx[o] = fmaf(vx, wv, accx[o]);
                        accs[o] = fmaf(vs, wv, accs[o]);
                    }
                }
            }
        } else {
            const int i00 = cy0 * WW + cx0, i01 = cy0 * WW + cx1;
            const int i10 = cy1 * WW + cx0, i11 = cy1 * WW + cx1;
#pragma unroll
            for (int c = 0; c < 8; c++) {
                const unsigned int* xc = xsb + (size_t)c * HWC;
                unsigned int a = xc[i00], bq = xc[i01], cq = xc[i10], dq = xc[i11];
                float x00 = __uint_as_float(a << 16),  s00 = __uint_as_float(a & 0xffff0000u);
                float x01 = __uint_as_float(bq << 16), s01 = __uint_as_float(bq & 0xffff0000u);
                float x10 = __uint_as_float(cq << 16), s10 = __uint_as_float(cq & 0xffff0000u);
                float x11 = __uint_as_float(dq << 16), s11 = __uint_as_float(dq & 0xffff0000u);
                float vx = w00 * x00; vx = fmaf(w01, x01, vx); vx = fmaf(w10, x10, vx); vx = fmaf(w11, x11, vx);
                float vs = w00 * s00; vs = fmaf(w01, s01, vs); vs = fmaf(w10, s10, vs); vs = fmaf(w11, s11, vs);
                vx *= m1;
                vs *= m2;
#pragma unroll
                for (int o = 0; o < 8; o++) {
                    const float wv = wk[(size_t)(o * 8 + c) * 9];
                    accx[o] = fmaf(vx, wv, accx[o]);
                    accs[o] = fmaf(vs, wv, accs[o]);
                }
            }
        }
    }

#pragma unroll
    for (int o = 0; o < 8; o++) {
        const float bv = bdc[g * 8 + o];
        outx[((size_t)(b * COO + g * 8 + o)) * HWC + pix] = accx[o] + bv;
        outs[((size_t)(b * COO + g * 8 + o)) * HWC + pix] = accs[o] + bv;
    }
}

// ---------------------------------------------------------------------------
extern "C" void kernel_launch(void* const* d_in, const int* in_sizes, int n_in,
                              void* d_out, int out_size, void* d_ws, size_t ws_size,
                              hipStream_t stream) {
    const float* x      = (const float*)d_in[0];
    const float* share  = (const float*)d_in[1];
    const float* offf   = (const float*)d_in[2];
    const float* w_om   = (const float*)d_in[3];
    const float* b_om   = (const float*)d_in[4];
    const float* w_em1  = (const float*)d_in[5];
    const float* b_em1  = (const float*)d_in[6];
    const float* w_em2  = (const float*)d_in[7];
    const float* b_em2  = (const float*)d_in[8];
    const float* w_dc   = (const float*)d_in[9];
    const float* b_dc   = (const float*)d_in[10];

    // Workspace layout (same total footprint as R12: dd replaces om_b+em_b)
    unsigned int* xs = (unsigned int*)d_ws;           // 4194304 u32
    unsigned short* us = (unsigned short*)(xs + 4194304);
    unsigned short* sc16   = us;                      // 4194304 ush (share c16)
    unsigned short* oc16   = sc16 + 4194304;          // 4194304 (offf c16)
    unsigned short* emm    = oc16 + 4194304;          // 4194304 (em_mid c16)
    unsigned short* dd     = emm + 4194304;           // 18874368 (4*PS8 + half)
    unsigned short* wp_om  = dd + 18874368;           // 147456 (COP=256)
    unsigned short* wp_em1 = wp_om + 147456;          // 73728  (COP=64)
    unsigned short* wp_em2 = wp_em1 + 73728;          // 73728  (COP=128)

    float* outx = (float*)d_out;
    float* outs = outx + 4194304;

    dim3 blk(256);

    // Fused input + weight packing (2 launches)
    pack_inputs_kernel<<<dim3(HWC / 64, BB), blk, 0, stream>>>(x, share, offf, xs, sc16, oc16);
    pack_w_all_kernel<<<(147456 + 73728 + 73728) / 256, blk, 0, stream>>>(
        w_om, wp_om, w_em1, wp_em1, w_em2, wp_em2);

    // om = conv(offset_feat) 64->216, sigmoid on mask channels -> dd slots
    conv_mfma_kernel<1, 256, 4><<<dim3(BB * 32 * 4, 7), blk, 0, stream>>>(
        oc16, nullptr, wp_om, b_om, dd, 216, 3, 3);
    // em_mid = leaky(conv(concat(share, offf))) 128->64, c16 bf16
    conv_mfma_kernel<2, 64, 4><<<dim3(BB * 32 * 4, 2), blk, 0, stream>>>(
        sc16, oc16, wp_em1, b_em1, emm, 64, 0, 1);
    // em = sigmoid(conv(em_mid)) 64->72 -> dd m2 slots
    conv_mfma_kernel<1, 128, 4><<<dim3(BB * 32 * 4, 3), blk, 0, stream>>>(
        emm, nullptr, wp_em2, b_em2, dd, 72, 4, 2);

    // fused dual deformable conv (LDS window + 5-vector offset loads)
    deform_fused_kernel<<<dim3(BB * GG * 64), blk, 0, stream>>>(
        xs, dd, w_dc, b_dc, outx, outs);
}